// Round 1
// baseline (499.030 us; speedup 1.0000x reference)
//
#include <hip/hip_runtime.h>
#include <math.h>

constexpr int IN_F = 128, OUT_F = 256, NH = 4, HD = 64;
constexpr int B = 8, N = 1024;
#define NEG 0.2f

// ---------------- Kernel 1: h = x @ W, plus per-node head scores ----------------
// grid = B*N/8 blocks, 256 threads. Each block computes 8 rows of h (8 x 256).
__global__ __launch_bounds__(256) void k_gemm(
    const float* __restrict__ x,    // [B*N, 128]
    const float* __restrict__ W,    // [128, 256]
    const float* __restrict__ a,    // [128]
    float* __restrict__ hfeat,      // [B*N, 256]
    float* __restrict__ si_g,       // [B*N, 4]
    float* __restrict__ sj_g)       // [B*N, 4]
{
    constexpr int ROWS = 8;
    __shared__ float xs[ROWS][IN_F];   // 4 KB
    const int t = threadIdx.x;
    const int row0 = blockIdx.x * ROWS;

    // stage 8 x-rows: 1024 floats = 256 float4
    ((float4*)xs)[t] = ((const float4*)(x + (size_t)row0 * IN_F))[t];
    __syncthreads();

    float acc[ROWS];
#pragma unroll
    for (int r = 0; r < ROWS; ++r) acc[r] = 0.f;
    for (int k = 0; k < IN_F; ++k) {
        const float w = W[k * OUT_F + t];   // coalesced across t
#pragma unroll
        for (int r = 0; r < ROWS; ++r) acc[r] = fmaf(xs[r][k], w, acc[r]);
    }

    const int lane = t & 63, head = t >> 6;   // wave w == head w (threads 0-63 = head 0)
    const float ai = a[lane], aj = a[HD + lane];
#pragma unroll
    for (int r = 0; r < ROWS; ++r) {
        const int row = row0 + r;
        hfeat[(size_t)row * OUT_F + t] = acc[r];
        float si = acc[r] * ai;
        float sj = acc[r] * aj;
#pragma unroll
        for (int off = 32; off; off >>= 1) {
            si += __shfl_xor(si, off, 64);
            sj += __shfl_xor(sj, off, 64);
        }
        if (lane == 0) {
            si_g[row * NH + head] = si;
            sj_g[row * NH + head] = sj;
        }
    }
}

// ---------------- Kernel 2: masked softmax over j + PV ----------------
// grid = B*N blocks (one per (b,i)), 256 threads.
__global__ __launch_bounds__(256) void k_attn(
    const float* __restrict__ hfeat,   // [B*N, 256]
    const float* __restrict__ si_g,    // [B*N, 4]
    const float* __restrict__ sj_g,    // [B*N, 4]
    const int* __restrict__ adj,       // [B, N, N]
    float* __restrict__ out)           // [B*N, 256]
{
    __shared__ float wls[N][NH];   // 16 KB: softmax weights per (j, head)
    __shared__ float red[4][NH];   // cross-wave reduction scratch

    const int bi = blockIdx.x;          // b*N + i
    const int b = bi >> 10;
    const int t = threadIdx.x, lane = t & 63, wv = t >> 6;

    const float4 si4 = *(const float4*)(si_g + (size_t)bi * NH);
    const float si[4] = {si4.x, si4.y, si4.z, si4.w};
    const int4 av = ((const int4*)(adj + (size_t)bi * N))[t];   // j = 4t..4t+3
    const int am[4] = {av.x, av.y, av.z, av.w};
    const float4* sjb = (const float4*)(sj_g + (size_t)b * N * NH);

    // ---- phase A: e = mask(lrelu(s_i + s_j)), kept in registers; per-head max
    float e_r[4][4];
    float pm[4] = {-INFINITY, -INFINITY, -INFINITY, -INFINITY};
#pragma unroll
    for (int jj = 0; jj < 4; ++jj) {
        const int j = 4 * t + jj;
        const float4 sj4 = sjb[j];
        const float sj[4] = {sj4.x, sj4.y, sj4.z, sj4.w};
#pragma unroll
        for (int h = 0; h < 4; ++h) {
            float e = si[h] + sj[h];
            e = (e >= 0.f) ? e : NEG * e;
            e = (am[jj] != 0) ? e : -INFINITY;
            e_r[jj][h] = e;
            pm[h] = fmaxf(pm[h], e);
        }
    }
    // max reduce: wave shuffle then cross-wave via LDS
#pragma unroll
    for (int h = 0; h < 4; ++h) {
        float v = pm[h];
#pragma unroll
        for (int off = 32; off; off >>= 1) v = fmaxf(v, __shfl_xor(v, off, 64));
        if (lane == 0) red[wv][h] = v;
    }
    __syncthreads();
    float mx[4];
#pragma unroll
    for (int h = 0; h < 4; ++h)
        mx[h] = fmaxf(fmaxf(red[0][h], red[1][h]), fmaxf(red[2][h], red[3][h]));
    __syncthreads();   // red reused below

    // ---- phase B: w = exp(e - mx), write to LDS, per-head sum
    float ps[4] = {0.f, 0.f, 0.f, 0.f};
#pragma unroll
    for (int jj = 0; jj < 4; ++jj) {
        const int j = 4 * t + jj;
        float w[4];
#pragma unroll
        for (int h = 0; h < 4; ++h) {
            w[h] = __expf(e_r[jj][h] - mx[h]);   // exp(-inf) = 0 handles the mask
            ps[h] += w[h];
        }
        *(float4*)&wls[j][0] = make_float4(w[0], w[1], w[2], w[3]);
    }
#pragma unroll
    for (int h = 0; h < 4; ++h) {
        float v = ps[h];
#pragma unroll
        for (int off = 32; off; off >>= 1) v += __shfl_xor(v, off, 64);
        if (lane == 0) red[wv][h] = v;
    }
    __syncthreads();   // also makes all wls writes visible
    const int head = t >> 6;
    const float Z = red[0][head] + red[1][head] + red[2][head] + red[3][head];
    const float invZ = 1.f / Z;

    // ---- phase C: out[t] = invZ * sum_j w[j][head] * h[b,j,t]
    const float* __restrict__ hb = hfeat + (size_t)b * N * OUT_F + t;
    float acc = 0.f;
    for (int j = 0; j < N; ++j) {
        const float w = wls[j][head];          // wave-uniform broadcast
        if (w != 0.f)                          // wave-uniform skip (~50% of j)
            acc = fmaf(w, hb[(size_t)j * OUT_F], acc);
    }
    out[(size_t)bi * OUT_F + t] = acc * invZ;
}

extern "C" void kernel_launch(void* const* d_in, const int* in_sizes, int n_in,
                              void* d_out, int out_size, void* d_ws, size_t ws_size,
                              hipStream_t stream) {
    const float* x   = (const float*)d_in[0];
    const int*   adj = (const int*)d_in[1];
    const float* W   = (const float*)d_in[2];
    const float* a   = (const float*)d_in[3];
    float* out = (float*)d_out;

    float* hfeat = (float*)d_ws;                          // 8 MB
    float* si_g  = hfeat + (size_t)B * N * OUT_F;         // 128 KB
    float* sj_g  = si_g + (size_t)B * N * NH;             // 128 KB

    k_gemm<<<B * N / 8, 256, 0, stream>>>(x, W, a, hfeat, si_g, sj_g);
    k_attn<<<B * N, 256, 0, stream>>>(hfeat, si_g, sj_g, adj, out);
}

// Round 2
// 65.597 us; speedup vs baseline: 7.6075x; 7.6075x over previous
//
#include <hip/hip_runtime.h>
#include <hip/hip_bf16.h>
#include <math.h>

constexpr int IN_F = 128, OUT_F = 256, NH = 4, HD = 64;
constexpr int B = 8, N = 1024;
#define NEG 0.2f

typedef __attribute__((ext_vector_type(8))) short bf16x8;
typedef __attribute__((ext_vector_type(4))) float f32x4;
typedef __attribute__((ext_vector_type(8))) unsigned short u16x8;

static __device__ __forceinline__ short f2bf(float f) {
    union { float f; unsigned u; } v; v.f = f;
    unsigned r = (v.u + 0x7FFF + ((v.u >> 16) & 1)) >> 16;   // RNE
    return (short)r;
}

// ---------------- Kernel 1: h = x @ W  ->  hT (bf16, [B][H][64][N]) + scores ----------------
// grid = B*N/8 blocks, 256 threads. Each block computes 8 rows of h (8 x 256).
__global__ __launch_bounds__(256) void k_gemm(
    const float* __restrict__ x,          // [B*N, 128]
    const float* __restrict__ W,          // [128, 256]
    const float* __restrict__ a,          // [128]
    unsigned short* __restrict__ hT,      // [B][H][64][N] bf16 bits (transposed!)
    float* __restrict__ siT,              // [B][H][N]
    float* __restrict__ sjT)              // [B][H][N]
{
    constexpr int ROWS = 8;
    __shared__ float xs[ROWS][IN_F];   // 4 KB
    const int t = threadIdx.x;
    const int row0 = blockIdx.x * ROWS;

    ((float4*)xs)[t] = ((const float4*)(x + (size_t)row0 * IN_F))[t];
    __syncthreads();

    float acc[ROWS];
#pragma unroll
    for (int r = 0; r < ROWS; ++r) acc[r] = 0.f;
    for (int k = 0; k < IN_F; ++k) {
        const float w = W[k * OUT_F + t];   // coalesced across t
#pragma unroll
        for (int r = 0; r < ROWS; ++r) acc[r] = fmaf(xs[r][k], w, acc[r]);
    }

    const int lane = t & 63, head = t >> 6, d = t & 63;
    const int b = row0 >> 10, n0 = row0 & (N - 1);   // blocks never straddle a batch (1024 % 8 == 0)

    // transposed bf16 store: thread owns column (head,d), 8 consecutive n -> one 16B store
    u16x8 pk;
#pragma unroll
    for (int r = 0; r < ROWS; ++r) pk[r] = (unsigned short)f2bf(acc[r]);
    *(u16x8*)&hT[((size_t)(b * NH + head) * HD + d) * N + n0] = pk;

    const float ai = a[lane], aj = a[HD + lane];
#pragma unroll
    for (int r = 0; r < ROWS; ++r) {
        float si = acc[r] * ai;
        float sj = acc[r] * aj;
#pragma unroll
        for (int off = 32; off; off >>= 1) {
            si += __shfl_xor(si, off, 64);
            sj += __shfl_xor(sj, off, 64);
        }
        if (lane == 0) {
            siT[(size_t)(b * NH + head) * N + n0 + r] = si;
            sjT[(size_t)(b * NH + head) * N + n0 + r] = sj;
        }
    }
}

// ---------------- Kernel 2: MFMA PV with on-the-fly P and deferred normalization ----------------
// grid = B * H * (N/64) = 512 blocks, 256 threads (4 waves).
// Block: (b, head h, i-tile of 64). Wave w owns i-rows [i0+16w, i0+16w+16).
// K-loop over j in steps of 32 using mfma_f32_16x16x32_bf16.
__global__ __launch_bounds__(256) void k_pv(
    const unsigned short* __restrict__ hT,   // [B][H][64][N] bf16
    const float* __restrict__ siT,           // [B][H][N]
    const float* __restrict__ sjT,           // [B][H][N]
    const int* __restrict__ adj,             // [B][N][N]
    float* __restrict__ out)                 // [B][N][256]
{
    constexpr int TJ = 32, PADJ = 40;        // LDS row padded to 40 elems (80 B) -> 2-way max
    __shared__ __align__(16) short ht[64 * PADJ];   // 5 KB  h-tile [d][k]
    __shared__ float sjs[N];                        // 4 KB  sj row for (b,h)
    __shared__ float zbuf[4][16];

    const int bid = blockIdx.x;
    const int it = bid & 15, h = (bid >> 4) & 3, b = bid >> 6;
    const int t = threadIdx.x, lane = t & 63, w = t >> 6;
    const int i0 = it * 64 + w * 16;

    // stage sj row (1024 floats, coalesced float4)
    ((float4*)sjs)[t] = ((const float4*)(sjT + (size_t)(b * NH + h) * N))[t];

    const int il = lane & 15, q = lane >> 4;     // A-row within frag, k-quarter
    const int i = i0 + il;                       // this lane's A (=P) row
    const float si = siT[(size_t)(b * NH + h) * N + i];
    const int4* __restrict__ arow = (const int4*)(adj + ((size_t)b * N + i) * N);
    const unsigned short* __restrict__ hTb = hT + (size_t)(b * NH + h) * HD * N;

    f32x4 acc0 = {0.f,0.f,0.f,0.f}, acc1 = {0.f,0.f,0.f,0.f};
    f32x4 acc2 = {0.f,0.f,0.f,0.f}, acc3 = {0.f,0.f,0.f,0.f};
    float psum = 0.f;

    // staging: thread t loads 16B of h-tile row (t>>2), col chunk (t&3)*8
    const int srow = t >> 2, sc = (t & 3) * 8;
    const unsigned short* __restrict__ hsrc = hTb + (size_t)srow * N + sc;
    short* __restrict__ hdst = &ht[srow * PADJ + sc];

    for (int j0 = 0; j0 < N; j0 += TJ) {
        __syncthreads();
        *(u16x8*)hdst = *(const u16x8*)(hsrc + j0);
        __syncthreads();

        // ---- A-frag: P[i][j0+q*8+e], e=0..7, generated in-register
        const int jq = j0 + q * 8;
        const int4 m0 = arow[jq >> 2];
        const int4 m1 = arow[(jq >> 2) + 1];
        const float4 s0 = *(const float4*)&sjs[jq];
        const float4 s1 = *(const float4*)&sjs[jq + 4];
        const float sv[8] = {s0.x, s0.y, s0.z, s0.w, s1.x, s1.y, s1.z, s1.w};
        const int   mv[8] = {m0.x, m0.y, m0.z, m0.w, m1.x, m1.y, m1.z, m1.w};
        bf16x8 af;
#pragma unroll
        for (int e = 0; e < 8; ++e) {
            float ev = si + sv[e];
            ev = (ev >= 0.f) ? ev : NEG * ev;
            const float pe = (mv[e] != 0) ? __expf(ev) : 0.f;   // unnormalized, |ev| small
            psum += pe;
            af[e] = f2bf(pe);
        }

        // ---- B-frags from LDS (ds_read_b128) + 4 MFMA
        const bf16x8 b0 = *(const bf16x8*)&ht[(0 * 16 + il) * PADJ + q * 8];
        const bf16x8 b1 = *(const bf16x8*)&ht[(1 * 16 + il) * PADJ + q * 8];
        const bf16x8 b2 = *(const bf16x8*)&ht[(2 * 16 + il) * PADJ + q * 8];
        const bf16x8 b3 = *(const bf16x8*)&ht[(3 * 16 + il) * PADJ + q * 8];
        acc0 = __builtin_amdgcn_mfma_f32_16x16x32_bf16(af, b0, acc0, 0, 0, 0);
        acc1 = __builtin_amdgcn_mfma_f32_16x16x32_bf16(af, b1, acc1, 0, 0, 0);
        acc2 = __builtin_amdgcn_mfma_f32_16x16x32_bf16(af, b2, acc2, 0, 0, 0);
        acc3 = __builtin_amdgcn_mfma_f32_16x16x32_bf16(af, b3, acc3, 0, 0, 0);
    }

    // ---- Z[i]: reduce psum over the 4 k-quarter lanes holding the same row
    psum += __shfl_xor(psum, 16, 64);
    psum += __shfl_xor(psum, 32, 64);
    if (lane < 16) zbuf[w][lane] = psum;
    __syncthreads();

    // ---- epilogue: C/D layout col = lane&15, row = q*4 + reg
    float iz[4];
#pragma unroll
    for (int r = 0; r < 4; ++r) iz[r] = 1.f / zbuf[w][q * 4 + r];

    float* __restrict__ ob = out + ((size_t)b * N + i0) * OUT_F + h * HD + il;
#pragma unroll
    for (int r = 0; r < 4; ++r) {
        float* o = ob + (size_t)(q * 4 + r) * OUT_F;
        o[0]  = acc0[r] * iz[r];
        o[16] = acc1[r] * iz[r];
        o[32] = acc2[r] * iz[r];
        o[48] = acc3[r] * iz[r];
    }
}

extern "C" void kernel_launch(void* const* d_in, const int* in_sizes, int n_in,
                              void* d_out, int out_size, void* d_ws, size_t ws_size,
                              hipStream_t stream) {
    const float* x   = (const float*)d_in[0];
    const int*   adj = (const int*)d_in[1];
    const float* W   = (const float*)d_in[2];
    const float* a   = (const float*)d_in[3];
    float* out = (float*)d_out;

    unsigned short* hT = (unsigned short*)d_ws;              // 4 MB bf16
    float* siT = (float*)(hT + (size_t)B * NH * HD * N);     // 128 KB
    float* sjT = siT + (size_t)B * NH * N;                   // 128 KB

    k_gemm<<<B * N / 8, 256, 0, stream>>>(x, W, a, hT, siT, sjT);
    k_pv<<<B * NH * (N / 64), 256, 0, stream>>>(hT, siT, sjT, adj, out);
}

// Round 3
// 47.410 us; speedup vs baseline: 10.5259x; 1.3836x over previous
//
#include <hip/hip_runtime.h>
#include <math.h>

constexpr int IN_F = 128, OUT_F = 256, NH = 4, HD = 64;
constexpr int B = 8, N = 1024;
#define NEG 0.2f

typedef __attribute__((ext_vector_type(8))) short bf16x8;
typedef __attribute__((ext_vector_type(4))) float f32x4;
typedef __attribute__((ext_vector_type(8))) unsigned short u16x8;

static __device__ __forceinline__ short f2bf(float f) {
    union { float f; unsigned u; } v; v.f = f;
    unsigned r = (v.u + 0x7FFF + ((v.u >> 16) & 1)) >> 16;   // RNE
    return (short)r;
}

// ---------------- Kernel 1: h = x @ W  ->  hT (bf16, [B][H][64][N]) + scores ----------------
__global__ __launch_bounds__(256) void k_gemm(
    const float* __restrict__ x,          // [B*N, 128]
    const float* __restrict__ W,          // [128, 256]
    const float* __restrict__ a,          // [128]
    unsigned short* __restrict__ hT,      // [B][H][64][N] bf16 bits (transposed)
    float* __restrict__ siT,              // [B][H][N]
    float* __restrict__ sjT)              // [B][H][N]
{
    constexpr int ROWS = 8;
    __shared__ float xs[ROWS][IN_F];   // 4 KB
    const int t = threadIdx.x;
    const int row0 = blockIdx.x * ROWS;

    ((float4*)xs)[t] = ((const float4*)(x + (size_t)row0 * IN_F))[t];
    __syncthreads();

    float acc[ROWS];
#pragma unroll
    for (int r = 0; r < ROWS; ++r) acc[r] = 0.f;
    for (int k = 0; k < IN_F; ++k) {
        const float w = W[k * OUT_F + t];   // coalesced across t
#pragma unroll
        for (int r = 0; r < ROWS; ++r) acc[r] = fmaf(xs[r][k], w, acc[r]);
    }

    const int lane = t & 63, head = t >> 6, d = t & 63;
    const int b = row0 >> 10, n0 = row0 & (N - 1);

    u16x8 pk;
#pragma unroll
    for (int r = 0; r < ROWS; ++r) pk[r] = (unsigned short)f2bf(acc[r]);
    *(u16x8*)&hT[((size_t)(b * NH + head) * HD + d) * N + n0] = pk;

    const float ai = a[lane], aj = a[HD + lane];
#pragma unroll
    for (int r = 0; r < ROWS; ++r) {
        float si = acc[r] * ai;
        float sj = acc[r] * aj;
#pragma unroll
        for (int off = 32; off; off >>= 1) {
            si += __shfl_xor(si, off, 64);
            sj += __shfl_xor(sj, off, 64);
        }
        if (lane == 0) {
            siT[(size_t)(b * NH + head) * N + n0 + r] = si;
            sjT[(size_t)(b * NH + head) * N + n0 + r] = sj;
        }
    }
}

// ---------------- Kernel 2: MFMA PV, double-buffered + register-prefetched ----------------
// grid = B * H * (N/64) = 512 blocks, 256 threads (4 waves).
// TJ=64: two K=32 MFMA steps per iteration, one barrier per iteration.
__global__ __launch_bounds__(256) void k_pv(
    const unsigned short* __restrict__ hT,   // [B][H][64][N] bf16
    const float* __restrict__ siT,           // [B][H][N]
    const float* __restrict__ sjT,           // [B][H][N]
    const int* __restrict__ adj,             // [B][N][N]
    float* __restrict__ out)                 // [B][N][256]
{
    constexpr int TJ = 64, NIT = N / TJ, PADJ = 72;   // 72-short rows: staggered banks
    __shared__ __align__(16) short ht[2][64 * PADJ];  // 2 x 9 KB  h-tile [d][k]
    __shared__ float sjs[N];                          // 4 KB
    __shared__ float zbuf[4][16];

    const int bid = blockIdx.x;
    const int itile = bid & 15, h = (bid >> 4) & 3, b = bid >> 6;
    const int t = threadIdx.x, lane = t & 63, w = t >> 6;
    const int i0 = itile * 64 + w * 16;

    // stage sj row (1024 floats, coalesced)
    ((float4*)sjs)[t] = ((const float4*)(sjT + (size_t)(b * NH + h) * N))[t];

    const int il = lane & 15, q = lane >> 4;
    const int i = i0 + il;
    const float si = siT[(size_t)(b * NH + h) * N + i];
    const int4* __restrict__ arow = (const int4*)(adj + ((size_t)b * N + i) * N);
    const unsigned short* __restrict__ hTb = hT + (size_t)(b * NH + h) * HD * N;

    // staging: thread t owns h-tile row t>>2, col chunk (t&3)*16 (32 B = 2 x b128)
    const int srow = t >> 2, sc = (t & 3) * 16;
    const unsigned short* __restrict__ hsrc = hTb + (size_t)srow * N + sc;

    f32x4 acc0 = {0.f,0.f,0.f,0.f}, acc1 = {0.f,0.f,0.f,0.f};
    f32x4 acc2 = {0.f,0.f,0.f,0.f}, acc3 = {0.f,0.f,0.f,0.f};
    float psum = 0.f;
    const int qc = q * 8;

    // ---- prologue: prefetch tile 0 into registers
    u16x8 ha = *(const u16x8*)(hsrc);
    u16x8 hc = *(const u16x8*)(hsrc + 8);
    int4 ma0 = arow[qc >> 2];
    int4 ma1 = arow[(qc >> 2) + 1];
    int4 mb0 = arow[(32 + qc) >> 2];
    int4 mb1 = arow[((32 + qc) >> 2) + 1];

    __syncthreads();   // sjs visible; nothing has read ht yet

    for (int itr = 0; itr < NIT; ++itr) {
        const int j0 = itr * TJ;

        // write current tile into LDS buffer (double-buffered: safe w/ 1 barrier)
        short* __restrict__ hd = &ht[itr & 1][srow * PADJ + sc];
        *(u16x8*)hd = ha;
        *(u16x8*)(hd + 8) = hc;

        // prefetch next tile (wrap on last iter; always-valid, branch-free)
        const int jn = (j0 + TJ) & (N - 1);
        const u16x8 na = *(const u16x8*)(hsrc + jn);
        const u16x8 nc = *(const u16x8*)(hsrc + jn + 8);
        const int4 xa0 = arow[(jn + qc) >> 2];
        const int4 xa1 = arow[((jn + qc) >> 2) + 1];
        const int4 xb0 = arow[(jn + 32 + qc) >> 2];
        const int4 xb1 = arow[((jn + 32 + qc) >> 2) + 1];

        __syncthreads();   // ds_writes visible

        const short* __restrict__ hbuf = ht[itr & 1];

        // ---- k-step 0: j = j0 + qc + e
        {
            const int jq = j0 + qc;
            const float4 s0 = *(const float4*)&sjs[jq];
            const float4 s1 = *(const float4*)&sjs[jq + 4];
            const float sv[8] = {s0.x,s0.y,s0.z,s0.w,s1.x,s1.y,s1.z,s1.w};
            const int   mv[8] = {ma0.x,ma0.y,ma0.z,ma0.w,ma1.x,ma1.y,ma1.z,ma1.w};
            bf16x8 af;
#pragma unroll
            for (int e = 0; e < 8; ++e) {
                float ev = si + sv[e];
                ev = (ev >= 0.f) ? ev : NEG * ev;
                const float pe = (mv[e] != 0) ? __expf(ev) : 0.f;
                psum += pe;
                af[e] = f2bf(pe);
            }
            const bf16x8 b0 = *(const bf16x8*)&hbuf[(0 * 16 + il) * PADJ + qc];
            const bf16x8 b1 = *(const bf16x8*)&hbuf[(1 * 16 + il) * PADJ + qc];
            const bf16x8 b2 = *(const bf16x8*)&hbuf[(2 * 16 + il) * PADJ + qc];
            const bf16x8 b3 = *(const bf16x8*)&hbuf[(3 * 16 + il) * PADJ + qc];
            acc0 = __builtin_amdgcn_mfma_f32_16x16x32_bf16(af, b0, acc0, 0, 0, 0);
            acc1 = __builtin_amdgcn_mfma_f32_16x16x32_bf16(af, b1, acc1, 0, 0, 0);
            acc2 = __builtin_amdgcn_mfma_f32_16x16x32_bf16(af, b2, acc2, 0, 0, 0);
            acc3 = __builtin_amdgcn_mfma_f32_16x16x32_bf16(af, b3, acc3, 0, 0, 0);
        }
        // ---- k-step 1: j = j0 + 32 + qc + e
        {
            const int jq = j0 + 32 + qc;
            const float4 s0 = *(const float4*)&sjs[jq];
            const float4 s1 = *(const float4*)&sjs[jq + 4];
            const float sv[8] = {s0.x,s0.y,s0.z,s0.w,s1.x,s1.y,s1.z,s1.w};
            const int   mv[8] = {mb0.x,mb0.y,mb0.z,mb0.w,mb1.x,mb1.y,mb1.z,mb1.w};
            bf16x8 af;
#pragma unroll
            for (int e = 0; e < 8; ++e) {
                float ev = si + sv[e];
                ev = (ev >= 0.f) ? ev : NEG * ev;
                const float pe = (mv[e] != 0) ? __expf(ev) : 0.f;
                psum += pe;
                af[e] = f2bf(pe);
            }
            const bf16x8 b0 = *(const bf16x8*)&hbuf[(0 * 16 + il) * PADJ + 32 + qc];
            const bf16x8 b1 = *(const bf16x8*)&hbuf[(1 * 16 + il) * PADJ + 32 + qc];
            const bf16x8 b2 = *(const bf16x8*)&hbuf[(2 * 16 + il) * PADJ + 32 + qc];
            const bf16x8 b3 = *(const bf16x8*)&hbuf[(3 * 16 + il) * PADJ + 32 + qc];
            acc0 = __builtin_amdgcn_mfma_f32_16x16x32_bf16(af, b0, acc0, 0, 0, 0);
            acc1 = __builtin_amdgcn_mfma_f32_16x16x32_bf16(af, b1, acc1, 0, 0, 0);
            acc2 = __builtin_amdgcn_mfma_f32_16x16x32_bf16(af, b2, acc2, 0, 0, 0);
            acc3 = __builtin_amdgcn_mfma_f32_16x16x32_bf16(af, b3, acc3, 0, 0, 0);
        }

        // rotate prefetched registers
        ha = na; hc = nc; ma0 = xa0; ma1 = xa1; mb0 = xb0; mb1 = xb1;
    }

    // ---- Z[i]: reduce psum over the 4 k-quarter lanes holding the same row
    psum += __shfl_xor(psum, 16, 64);
    psum += __shfl_xor(psum, 32, 64);
    if (lane < 16) zbuf[w][lane] = psum;
    __syncthreads();

    // ---- epilogue: C/D layout col = lane&15, row = q*4 + reg
    float iz[4];
#pragma unroll
    for (int r = 0; r < 4; ++r) iz[r] = 1.f / zbuf[w][q * 4 + r];

    float* __restrict__ ob = out + ((size_t)b * N + i0) * OUT_F + h * HD + il;
#pragma unroll
    for (int r = 0; r < 4; ++r) {
        float* o = ob + (size_t)(q * 4 + r) * OUT_F;
        o[0]  = acc0[r] * iz[r];
        o[16] = acc1[r] * iz[r];
        o[32] = acc2[r] * iz[r];
        o[48] = acc3[r] * iz[r];
    }
}

extern "C" void kernel_launch(void* const* d_in, const int* in_sizes, int n_in,
                              void* d_out, int out_size, void* d_ws, size_t ws_size,
                              hipStream_t stream) {
    const float* x   = (const float*)d_in[0];
    const int*   adj = (const int*)d_in[1];
    const float* W   = (const float*)d_in[2];
    const float* a   = (const float*)d_in[3];
    float* out = (float*)d_out;

    unsigned short* hT = (unsigned short*)d_ws;              // 4 MB bf16
    float* siT = (float*)(hT + (size_t)B * NH * HD * N);     // 128 KB
    float* sjT = siT + (size_t)B * NH * N;                   // 128 KB

    k_gemm<<<B * N / 8, 256, 0, stream>>>(x, W, a, hT, siT, sjT);
    k_pv<<<B * NH * (N / 64), 256, 0, stream>>>(hT, siT, sjT, adj, out);
}